// Round 6
// baseline (18282.623 us; speedup 1.0000x reference)
//
#include <hip/hip_runtime.h>
#include <cstdint>
#include <cstddef>

#define BDIM 256
#define NWG  256

constexpr int B_ = 64, S_ = 1024, I_ = 128, H_ = 512, O_ = 128;
constexpr size_t HB = (size_t)H_ * B_;   // 32768 floats per slab [k][b]

// ---- workspace (floats): slabs ~1.06MB, optional XT +33.5MB ----
constexpr size_t Y1_OFF  = 0;             // 2 slots (ring): y1[t] at slot t&1, seed y1[-1] at slot 1
constexpr size_t Y2_OFF  = Y1_OFF + 2 * HB;
constexpr size_t RH0_OFF = Y2_OFF + 2 * HB;
constexpr size_t RH1_OFF = RH0_OFF + HB;
constexpr size_t Z0_OFF  = RH1_OFF + HB;
constexpr size_t Z1_OFF  = Z0_OFF + HB;
constexpr size_t BAR_OFF = Z1_OFF + HB;   // tree barrier: 34 lines x 64 uints
constexpr size_t BAR_WORDS = 34 * 64;
constexpr size_t SLAB_TOT = BAR_OFF + BAR_WORDS;
constexpr size_t XT_OFF  = SLAB_TOT;      // [t][i][b] transposed input (immutable during scan)
constexpr size_t XT_FLOATS = (size_t)S_ * I_ * B_;
constexpr size_t WS_NEED_XT_BYTES = (XT_OFF + XT_FLOATS) * 4;

// ---------------- LLC (agent-scope, L2-bypassing) access helpers ----------------
__device__ __forceinline__ float4 llc_load4(const float* p) {
  const unsigned long long* q = (const unsigned long long*)p;
  unsigned long long lo = __hip_atomic_load(q,     __ATOMIC_RELAXED, __HIP_MEMORY_SCOPE_AGENT);
  unsigned long long hi = __hip_atomic_load(q + 1, __ATOMIC_RELAXED, __HIP_MEMORY_SCOPE_AGENT);
  union { unsigned long long u[2]; float4 v; } c;
  c.u[0] = lo; c.u[1] = hi;
  return c.v;
}
__device__ __forceinline__ float llc_loadf(const float* p) {
  unsigned int u = __hip_atomic_load((const unsigned int*)p, __ATOMIC_RELAXED,
                                     __HIP_MEMORY_SCOPE_AGENT);
  union { unsigned int u; float f; } c; c.u = u;
  return c.f;
}
__device__ __forceinline__ void llc_storef(float* p, float x) {
  union { float f; unsigned int u; } c; c.f = x;
  __hip_atomic_store((unsigned int*)p, c.u, __ATOMIC_RELAXED, __HIP_MEMORY_SCOPE_AGENT);
}

// ---------------- init: seed ring slot-1 with h0, zero barrier ----------------
__global__ void k_init(const float* __restrict__ hidden, float* __restrict__ ws) {
  int idx = blockIdx.x * 256 + threadIdx.x;           // 2*HB + BAR_WORDS items
  if (idx < (int)(2 * HB)) {
    int l = idx >> 15, r = idx & 32767;
    int k = r >> 6, b = r & 63;
    ws[(l ? Y2_OFF : Y1_OFF) + HB + r] = hidden[b * 1024 + l * 512 + k];
  } else if (idx < (int)(2 * HB + BAR_WORDS)) {
    ((unsigned int*)(ws + BAR_OFF))[idx - 2 * HB] = 0u;
  }
}

// ---------------- input transpose: XT[t][i][b] = input[b][t][i] ----------------
__global__ void k_transpose_x(const float* __restrict__ in, float* __restrict__ Xt) {
  const size_t NQ = (size_t)B_ * S_ * I_ / 4;
  for (size_t q = (size_t)blockIdx.x * blockDim.x + threadIdx.x; q < NQ;
       q += (size_t)gridDim.x * blockDim.x) {
    int i4 = (int)(q & 31);
    int t  = (int)((q >> 5) & 1023);
    int b  = (int)(q >> 15);
    float4 v = *(const float4*)(in + ((size_t)b * 1024 + t) * 128 + i4 * 4);
    float* dst = Xt + (size_t)t * 8192 + (size_t)(i4 * 4) * 64 + b;
    dst[0] = v.x; dst[64] = v.y; dst[128] = v.z; dst[192] = v.w;
  }
}

// ---------------- dot helpers ----------------
__device__ __forceinline__ void fmas(float4& a, float s, const float4 h) {
  a.x = fmaf(s, h.x, a.x); a.y = fmaf(s, h.y, a.y);
  a.z = fmaf(s, h.z, a.z); a.w = fmaf(s, h.w, a.w);
}

// plain C=8 dot over a mutable slab region (L0 region 1)
__device__ __forceinline__ void dotA8(const float* __restrict__ src, const float* __restrict__ wAp,
                                      int kt, int b4, float4* acc) {
  #pragma unroll 8
  for (int ch = 0; ch < 32; ++ch) {
    int kk = ch * 16 + kt;
    float4 h = llc_load4(src + (size_t)kk * 64 + b4);
    const float* wp = wAp + kk * 8;
    float4 w0 = *(const float4*)wp;
    float4 w1 = *(const float4*)(wp + 4);
    fmas(acc[0], w0.x, h); fmas(acc[1], w0.y, h); fmas(acc[2], w0.z, h); fmas(acc[3], w0.w, h);
    fmas(acc[4], w1.x, h); fmas(acc[5], w1.y, h); fmas(acc[6], w1.z, h); fmas(acc[7], w1.w, h);
  }
}

// fused L1 region1 (y1p): A-gate 8 cols + g1 x-part 4 cols
__device__ __forceinline__ void fusedL1r1(const float* __restrict__ src,
                                          const float* __restrict__ wAp,
                                          const float* __restrict__ wBp,
                                          int kt, int b4, float4* acc, float4* accB) {
  #pragma unroll 8
  for (int ch = 0; ch < 32; ++ch) {
    int kk = ch * 16 + kt;
    float4 h = llc_load4(src + (size_t)kk * 64 + b4);
    const float* wp = wAp + kk * 8;
    float4 w0 = *(const float4*)wp;
    float4 w1 = *(const float4*)(wp + 4);
    fmas(acc[0], w0.x, h); fmas(acc[1], w0.y, h); fmas(acc[2], w0.z, h); fmas(acc[3], w0.w, h);
    fmas(acc[4], w1.x, h); fmas(acc[5], w1.y, h); fmas(acc[6], w1.z, h); fmas(acc[7], w1.w, h);
    const float* gp = wBp + kk * 4;
    float4 g0 = *(const float4*)gp;
    fmas(accB[0], g0.x, h); fmas(accB[1], g0.y, h); fmas(accB[2], g0.z, h); fmas(accB[3], g0.w, h);
  }
}

// fused L1 region2 (y2p): A-gate h-part 8 cols + outproj 1 col
__device__ __forceinline__ void fusedL1r2(const float* __restrict__ src,
                                          const float* __restrict__ wAp2,
                                          const float* __restrict__ wOp,
                                          int kt, int b4, float4* acc, float4& accO) {
  #pragma unroll 8
  for (int ch = 0; ch < 32; ++ch) {
    int kk = ch * 16 + kt;
    float4 h = llc_load4(src + (size_t)kk * 64 + b4);
    const float* wp = wAp2 + kk * 8;
    float4 w0 = *(const float4*)wp;
    float4 w1 = *(const float4*)(wp + 4);
    fmas(acc[0], w0.x, h); fmas(acc[1], w0.y, h); fmas(acc[2], w0.z, h); fmas(acc[3], w0.w, h);
    fmas(acc[4], w1.x, h); fmas(acc[5], w1.y, h); fmas(acc[6], w1.z, h); fmas(acc[7], w1.w, h);
    fmas(accO, wOp[kk], h);
  }
}

// fused L0 x-region (XT, cached/immutable): A-gate x-part 8 cols + g0 x-part 4 cols
__device__ __forceinline__ void fusedL0x(const float* __restrict__ src,
                                         const float* __restrict__ wAp2,
                                         const float* __restrict__ wBp2,
                                         int kt, int b4, float4* acc, float4* accB) {
  #pragma unroll 8
  for (int ch = 0; ch < 8; ++ch) {
    int i = ch * 16 + kt;
    float4 h = *(const float4*)(src + (size_t)i * 64 + b4);
    const float* wp = wAp2 + i * 8;
    float4 w0 = *(const float4*)wp;
    float4 w1 = *(const float4*)(wp + 4);
    fmas(acc[0], w0.x, h); fmas(acc[1], w0.y, h); fmas(acc[2], w0.z, h); fmas(acc[3], w0.w, h);
    fmas(acc[4], w1.x, h); fmas(acc[5], w1.y, h); fmas(acc[6], w1.z, h); fmas(acc[7], w1.w, h);
    const float* gp = wBp2 + i * 4;
    float4 g0 = *(const float4*)gp;
    fmas(accB[0], g0.x, h); fmas(accB[1], g0.y, h); fmas(accB[2], g0.z, h); fmas(accB[3], g0.w, h);
  }
}

// fallback: L0 x-region straight from input[b][t][i]
__device__ __forceinline__ void fusedL0xf(const float* __restrict__ xin, int tau,
                                          const float* __restrict__ wAp2,
                                          const float* __restrict__ wBp2,
                                          int kt, int b4, float4* acc, float4* accB) {
  #pragma unroll 2
  for (int ch = 0; ch < 8; ++ch) {
    int i = ch * 16 + kt;
    float4 h;
    h.x = xin[(size_t)(b4 + 0) * 131072 + tau * 128 + i];
    h.y = xin[(size_t)(b4 + 1) * 131072 + tau * 128 + i];
    h.z = xin[(size_t)(b4 + 2) * 131072 + tau * 128 + i];
    h.w = xin[(size_t)(b4 + 3) * 131072 + tau * 128 + i];
    const float* wp = wAp2 + i * 8;
    float4 w0 = *(const float4*)wp;
    float4 w1 = *(const float4*)(wp + 4);
    fmas(acc[0], w0.x, h); fmas(acc[1], w0.y, h); fmas(acc[2], w0.z, h); fmas(acc[3], w0.w, h);
    fmas(acc[4], w1.x, h); fmas(acc[5], w1.y, h); fmas(acc[6], w1.z, h); fmas(acc[7], w1.w, h);
    const float* gp = wBp2 + i * 4;
    float4 g0 = *(const float4*)gp;
    fmas(accB[0], g0.x, h); fmas(accB[1], g0.y, h); fmas(accB[2], g0.z, h); fmas(accB[3], g0.w, h);
  }
}

// C=4 dot over a mutable slab region (phase B: rh only)
__device__ __forceinline__ void dotB4(const float* __restrict__ src, const float* __restrict__ wBp,
                                      int kt, int b4, float4* acc) {
  #pragma unroll 8
  for (int ch = 0; ch < 32; ++ch) {
    int kk = ch * 16 + kt;
    float4 h = llc_load4(src + (size_t)kk * 64 + b4);
    const float* wp = wBp + kk * 4;
    float4 w0 = *(const float4*)wp;
    fmas(acc[0], w0.x, h); fmas(acc[1], w0.y, h); fmas(acc[2], w0.z, h); fmas(acc[3], w0.w, h);
  }
}

// ---- fence-free two-level tree barrier (all cross-WG data is LLC-coherent) ----
__device__ __forceinline__ void grid_barrier(unsigned int* bar, unsigned int ph) {
  __syncthreads();
  asm volatile("" ::: "memory");
  if (threadIdx.x == 0) {
    const int g = (int)(blockIdx.x >> 4);
    unsigned int* grp_cnt  = bar + (size_t)g * 64;
    unsigned int* root_cnt = bar + 16 * 64;
    unsigned int* grp_gen  = bar + (size_t)(17 + g) * 64;
    unsigned int* root_gen = bar + 33 * 64;
    unsigned int r = __hip_atomic_fetch_add(grp_cnt, 1u, __ATOMIC_RELAXED, __HIP_MEMORY_SCOPE_AGENT);
    if (r == 16u * ph - 1u) {
      unsigned int rr = __hip_atomic_fetch_add(root_cnt, 1u, __ATOMIC_RELAXED, __HIP_MEMORY_SCOPE_AGENT);
      if (rr == 16u * ph - 1u) {
        __hip_atomic_store(root_gen, ph, __ATOMIC_RELAXED, __HIP_MEMORY_SCOPE_AGENT);
      } else {
        while (__hip_atomic_load(root_gen, __ATOMIC_RELAXED, __HIP_MEMORY_SCOPE_AGENT) < ph)
          __builtin_amdgcn_s_sleep(1);
      }
      __hip_atomic_store(grp_gen, ph, __ATOMIC_RELAXED, __HIP_MEMORY_SCOPE_AGENT);
    } else {
      while (__hip_atomic_load(grp_gen, __ATOMIC_RELAXED, __HIP_MEMORY_SCOPE_AGENT) < ph)
        __builtin_amdgcn_s_sleep(1);
    }
  }
  asm volatile("" ::: "memory");
  __syncthreads();
}

// ---------------- persistent scan ----------------
struct ScanArgs {
  float* ws;
  const float* xin;
  float* out;
  const float *Wzx0, *Wzh0, *bz0, *Wrx0, *Wrh0, *br0, *Wgx0, *Wgh0, *bg0;
  const float *Wzx1, *Wzh1, *bz1, *Wrx1, *Wrh1, *br1, *Wgx1, *Wgh1, *bg1;
  const float *Wout, *bout;
  int use_xt;
};

__launch_bounds__(BDIM, 1)
__global__ void k_scan(ScanArgs a) {
  float* ws = a.ws;
  unsigned int* bar = (unsigned int*)(ws + BAR_OFF);

  const int tid = threadIdx.x;
  const int wg  = blockIdx.x;
  const int kt  = tid >> 4;          // 0..15 (k-thread)
  const int bq  = tid & 15;          // 0..15 (batch quad)
  const int b4  = bq << 2;           // batch base

  // phase A: wg>>6 -> {L0z, L0r, L1z, L1r}, 8 cols each
  const int mA  = wg >> 6;
  const int lA  = mA >> 1;
  const int gA  = mA & 1;
  const int jA0 = (wg & 63) * 8;
  const int KA  = (mA < 2) ? 640 : 1024;
  // phase B: wg>>7 -> {L0g, L1g}, 4 cols each
  const int mB  = wg >> 7;
  const int jB0 = (wg & 127) * 4;
  const int KB  = mB ? 1024 : 640;
  // outproj: L1 WGs (wg>=128), 1 col each
  const int oc  = wg - 128;

  __shared__ float wA[8192];         // [k][8] A-gate weights
  __shared__ float wB[4096];         // [k][4] g-gate weights
  __shared__ float wO[512];          // outproj column (wg>=128)
  __shared__ float pA[9 * 64 * 17];  // partials: [c(9)][b(64)][kt(17)]

  {  // one-time gather (cached loads; immutable inputs)
    const float* A0 = lA ? (gA ? a.Wrx1 : a.Wzx1) : (gA ? a.Wrh0 : a.Wzh0);
    const float* A1 = lA ? (gA ? a.Wrh1 : a.Wzh1) : (gA ? a.Wrx0 : a.Wzx0);
    for (int idx = tid; idx < KA * 8; idx += BDIM) {
      int k = idx >> 3, c = idx & 7;
      wA[idx] = (k < 512) ? A0[k * 512 + jA0 + c] : A1[(k - 512) * 512 + jA0 + c];
    }
    const float* B0 = mB ? a.Wgx1 : a.Wgh0;
    const float* B1 = mB ? a.Wgh1 : a.Wgx0;
    for (int idx = tid; idx < KB * 4; idx += BDIM) {
      int k = idx >> 2, c = idx & 3;
      wB[idx] = (k < 512) ? B0[k * 512 + jB0 + c] : B1[(k - 512) * 512 + jB0 + c];
    }
    if (wg >= 128)
      for (int idx = tid; idx < 512; idx += BDIM) wO[idx] = a.Wout[(size_t)idx * 128 + oc];
  }
  const float* bAv = lA ? (gA ? a.br1 : a.bz1) : (gA ? a.br0 : a.bz0);
  const float biasA_0 = bAv[jA0 + (tid >> 6)];
  const float biasA_1 = bAv[jA0 + 4 + (tid >> 6)];
  const float biasB_0 = (mB ? a.bg1 : a.bg0)[jB0 + (tid >> 6)];
  const float boutW = (wg >= 128) ? a.bout[oc] : 0.f;
  __syncthreads();

  const float* XT = ws + XT_OFF;
  unsigned int ph = 1;

  for (int tau = 0; tau <= S_ + 1; ++tau) {
    const bool doL0 = (tau < S_);
    const bool doL1 = (tau >= 1) && (tau <= S_);
    const int slotP = (tau + 1) & 1;
    const int slotQ = tau & 1;
    const float* y1p = ws + Y1_OFF + (size_t)slotP * HB;   // y1[tau-1]
    const float* y2p = ws + Y2_OFF + (size_t)slotQ * HB;   // y2[tau-2]
    float* y1w = ws + Y1_OFF + (size_t)slotQ * HB;
    float* y2w = ws + Y2_OFF + (size_t)slotP * HB;

    // ============ phase A: z & r, + g x-part precompute, + fused outproj ============
    const bool actA = lA ? doL1 : doL0;
    const bool doOut = (tau >= 2) && (wg >= 128);
    float4 acc[8];
    float4 accB[4];    // g-gate x-part partial; persists across the barrier into phase B
    float4 accO = make_float4(0.f, 0.f, 0.f, 0.f);
    #pragma unroll
    for (int c = 0; c < 8; ++c) acc[c] = make_float4(0.f, 0.f, 0.f, 0.f);
    #pragma unroll
    for (int c = 0; c < 4; ++c) accB[c] = make_float4(0.f, 0.f, 0.f, 0.f);

    if (actA) {
      if (mA < 2) {   // L0: h-part from y1p, x-part (A + g0) from XT/xin
        dotA8(y1p, wA, kt, b4, acc);
        if (a.use_xt) fusedL0x(XT + (size_t)tau * 8192, wA + 512 * 8, wB + 512 * 4, kt, b4, acc, accB);
        else          fusedL0xf(a.xin, tau, wA + 512 * 8, wB + 512 * 4, kt, b4, acc, accB);
      } else {        // L1: x-part (A + g1) from y1p, h-part (A + outproj) from y2p
        fusedL1r1(y1p, wA, wB, kt, b4, acc, accB);
        fusedL1r2(y2p, wA + 512 * 8, wO, kt, b4, acc, accO);
      }
    } else if (tau == S_ + 1 && wg >= 128) {
      // standalone outproj tail for t = S-1
      #pragma unroll 8
      for (int ch = 0; ch < 32; ++ch) {
        int kk = ch * 16 + kt;
        float4 h = llc_load4(y2p + (size_t)kk * 64 + b4);
        fmas(accO, wO[kk], h);
      }
    }

    // partial store + reduce
    if (actA) {
      #pragma unroll
      for (int c = 0; c < 8; ++c) {
        float pv[4] = {acc[c].x, acc[c].y, acc[c].z, acc[c].w};
        #pragma unroll
        for (int j = 0; j < 4; ++j) pA[(c * 64 + b4 + j) * 17 + kt] = pv[j];
      }
    }
    if (doOut) {
      float pv[4] = {accO.x, accO.y, accO.z, accO.w};
      #pragma unroll
      for (int j = 0; j < 4; ++j) pA[(512 + b4 + j) * 17 + kt] = pv[j];
    }
    __syncthreads();
    if (actA) {
      #pragma unroll
      for (int r = 0; r < 2; ++r) {
        int idx = tid + (r << 8);
        int c = idx >> 6, b = idx & 63;
        float s = r ? biasA_1 : biasA_0;
        #pragma unroll
        for (int q = 0; q < 16; ++q) s += pA[(c * 64 + b) * 17 + q];
        float v = 1.0f / (1.0f + __expf(-s));
        size_t jb = (size_t)(jA0 + c) * 64 + b;
        if (gA == 0) {
          llc_storef(ws + (lA ? Z1_OFF : Z0_OFF) + jb, v);
        } else {
          const float* hpsl = lA ? y2p : y1p;
          float hp = llc_loadf(hpsl + jb);
          llc_storef(ws + (lA ? RH1_OFF : RH0_OFF) + jb, v * hp);
        }
      }
    }
    if (doOut && tid < 64) {
      float s = boutW;
      #pragma unroll
      for (int q = 0; q < 16; ++q) s += pA[(512 + tid) * 17 + q];
      a.out[((size_t)tid * 1024 + (tau - 2)) * 128 + oc] = s;
    }

    grid_barrier(bar, ph++);   // rh/z visible grid-wide

    // ============ phase B: g (rh-part only; x-part already in accB) + h update ============
    const bool actB = mB ? doL1 : doL0;
    if (actB) {
      if (mB == 0) dotB4(ws + RH0_OFF, wB, kt, b4, accB);            // W rows [0,512)
      else         dotB4(ws + RH1_OFF, wB + 512 * 4, kt, b4, accB);  // W rows [512,1024)
      #pragma unroll
      for (int c = 0; c < 4; ++c) {
        float pv[4] = {accB[c].x, accB[c].y, accB[c].z, accB[c].w};
        #pragma unroll
        for (int j = 0; j < 4; ++j) pA[(c * 64 + b4 + j) * 17 + kt] = pv[j];
      }
    }
    __syncthreads();
    if (actB) {
      int c = tid >> 6, b = tid & 63;
      float s = biasB_0;
      #pragma unroll
      for (int q = 0; q < 16; ++q) s += pA[(c * 64 + b) * 17 + q];
      float g = tanhf(s);
      size_t jb = (size_t)(jB0 + c) * 64 + b;
      float z  = llc_loadf(ws + (mB ? Z1_OFF : Z0_OFF) + jb);
      float hp = llc_loadf((mB ? y2p : y1p) + jb);
      float hn = fmaf(z, hp - g, g);
      llc_storef((mB ? y2w : y1w) + jb, hn);
    }

    grid_barrier(bar, ph++);   // h slabs visible for next stage
  }
}

// ---------------- final hidden states ----------------
__global__ void k_hidden(const float* __restrict__ ws, float* __restrict__ out) {
  int idx = blockIdx.x * 256 + threadIdx.x;   // 65536
  int b = idx >> 10, rem = idx & 1023, l = rem >> 9, j = rem & 511;
  const float* src = ws + (l ? Y2_OFF : Y1_OFF) + HB + (size_t)j * 64 + b;
  out[(size_t)B_ * S_ * O_ + idx] = *src;
}

// ---------------- launch ----------------
extern "C" void kernel_launch(void* const* d_in, const int* in_sizes, int n_in,
                              void* d_out, int out_size, void* d_ws, size_t ws_size,
                              hipStream_t stream) {
  const float* input  = (const float*)d_in[0];
  const float* hidden = (const float*)d_in[1];
  const float* Wzx0 = (const float*)d_in[2],  *Wzh0 = (const float*)d_in[3],  *bz0 = (const float*)d_in[4];
  const float* Wrx0 = (const float*)d_in[5],  *Wrh0 = (const float*)d_in[6],  *br0 = (const float*)d_in[7];
  const float* Wgx0 = (const float*)d_in[8],  *Wgh0 = (const float*)d_in[9],  *bg0 = (const float*)d_in[10];
  const float* Wzx1 = (const float*)d_in[11], *Wzh1 = (const float*)d_in[12], *bz1 = (const float*)d_in[13];
  const float* Wrx1 = (const float*)d_in[14], *Wrh1 = (const float*)d_in[15], *br1 = (const float*)d_in[16];
  const float* Wgx1 = (const float*)d_in[17], *Wgh1 = (const float*)d_in[18], *bg1 = (const float*)d_in[19];
  const float* Wout = (const float*)d_in[20], *bout = (const float*)d_in[21];
  float* ws = (float*)d_ws;
  float* out = (float*)d_out;

  const int use_xt = (ws_size >= WS_NEED_XT_BYTES) ? 1 : 0;

  k_init<<<265, BDIM, 0, stream>>>(hidden, ws);
  if (use_xt) k_transpose_x<<<2048, BDIM, 0, stream>>>(input, ws + XT_OFF);

  ScanArgs sa{ws, input, out,
              Wzx0, Wzh0, bz0, Wrx0, Wrh0, br0, Wgx0, Wgh0, bg0,
              Wzx1, Wzh1, bz1, Wrx1, Wrh1, br1, Wgx1, Wgh1, bg1,
              Wout, bout, use_xt};
  k_scan<<<dim3(NWG), dim3(BDIM), 0, stream>>>(sa);

  k_hidden<<<256, 256, 0, stream>>>(ws, out);
}